// Round 1
// baseline (1477.070 us; speedup 1.0000x reference)
//
#include <hip/hip_runtime.h>

#define IN_CH 64
#define HC 128          // HEADS * OUT_CH
#define NHEAD 4
#define NEG 0.2f

__device__ __forceinline__ float leaky(float v) { return v >= 0.f ? v : NEG * v; }

// monotonic float atomic max (no NaNs in this data path)
__device__ __forceinline__ void atomicMaxFloat(float* addr, float val) {
    if (val >= 0.f) atomicMax((int*)addr, __float_as_int(val));
    else            atomicMin((unsigned int*)addr, (unsigned int)__float_as_int(val));
}

// One block (128 threads) per node: h[n] = x[n] @ W ; a_src/a_dst reductions.
__global__ void k_transform(const float* __restrict__ x, const float* __restrict__ W,
                            const float* __restrict__ att_src, const float* __restrict__ att_dst,
                            float* __restrict__ h, float* __restrict__ a_src,
                            float* __restrict__ a_dst) {
    const int n = blockIdx.x;
    const int t = threadIdx.x;           // 0..127
    __shared__ float xs[IN_CH];
    if (t < IN_CH) xs[t] = x[(size_t)n * IN_CH + t];
    __syncthreads();
    float acc = 0.f;
#pragma unroll
    for (int k = 0; k < IN_CH; ++k)
        acc = fmaf(xs[k], W[k * HC + t], acc);
    h[(size_t)n * HC + t] = acc;

    float ps = acc * att_src[t];
    float pd = acc * att_dst[t];
#pragma unroll
    for (int off = 16; off > 0; off >>= 1) {
        ps += __shfl_down(ps, off, 32);
        pd += __shfl_down(pd, off, 32);
    }
    if ((t & 31) == 0) {
        a_src[n * NHEAD + (t >> 5)] = ps;
        a_dst[n * NHEAD + (t >> 5)] = pd;
    }
}

// m[i] = leaky(a_src[i] + a_dst[i])   (self-loop score as init for segment max)
__global__ void k_init_m(const float* __restrict__ a_src, const float* __restrict__ a_dst,
                         float* __restrict__ m, int NH) {
    int i = blockIdx.x * blockDim.x + threadIdx.x;
    if (i < NH) m[i] = leaky(a_src[i] + a_dst[i]);
}

__global__ void k_edge_max(const int* __restrict__ src, const int* __restrict__ dst,
                           const float* __restrict__ a_src, const float* __restrict__ a_dst,
                           float* __restrict__ m, int E) {
    int e = blockIdx.x * blockDim.x + threadIdx.x;
    if (e >= E) return;
    int s = src[e], d = dst[e];
    float4 as = *(const float4*)(a_src + 4 * (size_t)s);
    float4 ad = *(const float4*)(a_dst + 4 * (size_t)d);
    atomicMaxFloat(&m[4 * (size_t)d + 0], leaky(as.x + ad.x));
    atomicMaxFloat(&m[4 * (size_t)d + 1], leaky(as.y + ad.y));
    atomicMaxFloat(&m[4 * (size_t)d + 2], leaky(as.z + ad.z));
    atomicMaxFloat(&m[4 * (size_t)d + 3], leaky(as.w + ad.w));
}

// denom[i] = exp(e_self - m[i])  (self-loop contribution)
__global__ void k_denom_init(const float* __restrict__ a_src, const float* __restrict__ a_dst,
                             const float* __restrict__ m, float* __restrict__ denom, int NH) {
    int i = blockIdx.x * blockDim.x + threadIdx.x;
    if (i < NH) denom[i] = expf(leaky(a_src[i] + a_dst[i]) - m[i]);
}

__global__ void k_edge_denom(const int* __restrict__ src, const int* __restrict__ dst,
                             const float* __restrict__ a_src, const float* __restrict__ a_dst,
                             const float* __restrict__ m, float* __restrict__ denom, int E) {
    int e = blockIdx.x * blockDim.x + threadIdx.x;
    if (e >= E) return;
    int s = src[e], d = dst[e];
    float4 as = *(const float4*)(a_src + 4 * (size_t)s);
    float4 ad = *(const float4*)(a_dst + 4 * (size_t)d);
    float4 mm = *(const float4*)(m + 4 * (size_t)d);
    atomicAdd(&denom[4 * (size_t)d + 0], expf(leaky(as.x + ad.x) - mm.x));
    atomicAdd(&denom[4 * (size_t)d + 1], expf(leaky(as.y + ad.y) - mm.y));
    atomicAdd(&denom[4 * (size_t)d + 2], expf(leaky(as.z + ad.z) - mm.z));
    atomicAdd(&denom[4 * (size_t)d + 3], expf(leaky(as.w + ad.w) - mm.w));
}

// One wave (64 lanes) per edge; each lane handles channels lane and lane+64.
__global__ void k_edge_scatter(const int* __restrict__ src, const int* __restrict__ dst,
                               const float* __restrict__ a_src, const float* __restrict__ a_dst,
                               const float* __restrict__ m, const float* __restrict__ denom,
                               const float* __restrict__ h, float* __restrict__ out, int E) {
    const int lane = threadIdx.x & 63;
    const int e = blockIdx.x * (blockDim.x >> 6) + (threadIdx.x >> 6);
    if (e >= E) return;
    const int s = src[e], d = dst[e];
    float4 as = *(const float4*)(a_src + 4 * (size_t)s);
    float4 ad = *(const float4*)(a_dst + 4 * (size_t)d);
    float4 mm = *(const float4*)(m + 4 * (size_t)d);
    float4 dn = *(const float4*)(denom + 4 * (size_t)d);
    float al[NHEAD];
    al[0] = expf(leaky(as.x + ad.x) - mm.x) / (dn.x + 1e-16f);
    al[1] = expf(leaky(as.y + ad.y) - mm.y) / (dn.y + 1e-16f);
    al[2] = expf(leaky(as.z + ad.z) - mm.z) / (dn.z + 1e-16f);
    al[3] = expf(leaky(as.w + ad.w) - mm.w) / (dn.w + 1e-16f);
    const size_t sb = (size_t)s * HC, db = (size_t)d * HC;
    int c0 = lane, c1 = lane + 64;
    atomicAdd(&out[db + c0], al[c0 >> 5] * h[sb + c0]);
    atomicAdd(&out[db + c1], al[c1 >> 5] * h[sb + c1]);
}

// One block (128 threads) per node: add self-loop term + bias, log_softmax over 128.
__global__ void k_finalize(const float* __restrict__ a_src, const float* __restrict__ a_dst,
                           const float* __restrict__ m, const float* __restrict__ denom,
                           const float* __restrict__ h, const float* __restrict__ bias,
                           float* __restrict__ out) {
    const int n = blockIdx.x;
    const int t = threadIdx.x;           // 0..127
    const int hd = t >> 5;
    float es = leaky(a_src[n * NHEAD + hd] + a_dst[n * NHEAD + hd]);
    float mm = m[n * NHEAD + hd];
    float dn = denom[n * NHEAD + hd];
    float alpha = expf(es - mm) / (dn + 1e-16f);
    size_t idx = (size_t)n * HC + t;
    float v = out[idx] + alpha * h[idx] + bias[t];

    __shared__ float s1[2], s2[2];
    float mx = v;
#pragma unroll
    for (int off = 32; off > 0; off >>= 1) mx = fmaxf(mx, __shfl_down(mx, off, 64));
    if ((t & 63) == 0) s1[t >> 6] = mx;
    __syncthreads();
    mx = fmaxf(s1[0], s1[1]);
    float ex = expf(v - mx);
    float sm = ex;
#pragma unroll
    for (int off = 32; off > 0; off >>= 1) sm += __shfl_down(sm, off, 64);
    if ((t & 63) == 0) s2[t >> 6] = sm;
    __syncthreads();
    sm = s2[0] + s2[1];
    out[idx] = v - mx - logf(sm);
}

extern "C" void kernel_launch(void* const* d_in, const int* in_sizes, int n_in,
                              void* d_out, int out_size, void* d_ws, size_t ws_size,
                              hipStream_t stream) {
    const float* x       = (const float*)d_in[0];
    const int*   ei      = (const int*)d_in[1];
    const float* W       = (const float*)d_in[2];
    const float* att_src = (const float*)d_in[3];
    const float* att_dst = (const float*)d_in[4];
    const float* bias    = (const float*)d_in[5];
    float* out = (float*)d_out;

    const int N = in_sizes[0] / IN_CH;     // 100000
    const int E = in_sizes[1] / 2;         // 1600000
    const int* src = ei;
    const int* dst = ei + E;

    float* ws     = (float*)d_ws;
    float* h      = ws;                                    // N*128
    float* a_src  = h     + (size_t)N * HC;                // N*4
    float* a_dst  = a_src + (size_t)N * NHEAD;             // N*4
    float* m      = a_dst + (size_t)N * NHEAD;             // N*4
    float* denom  = m     + (size_t)N * NHEAD;             // N*4

    hipMemsetAsync(d_out, 0, (size_t)out_size * sizeof(float), stream);

    k_transform<<<N, HC, 0, stream>>>(x, W, att_src, att_dst, h, a_src, a_dst);

    const int NH = N * NHEAD;
    k_init_m<<<(NH + 255) / 256, 256, 0, stream>>>(a_src, a_dst, m, NH);
    k_edge_max<<<(E + 255) / 256, 256, 0, stream>>>(src, dst, a_src, a_dst, m, E);
    k_denom_init<<<(NH + 255) / 256, 256, 0, stream>>>(a_src, a_dst, m, denom, NH);
    k_edge_denom<<<(E + 255) / 256, 256, 0, stream>>>(src, dst, a_src, a_dst, m, denom, E);
    k_edge_scatter<<<(E + 3) / 4, 256, 0, stream>>>(src, dst, a_src, a_dst, m, denom, h, out, E);
    k_finalize<<<N, HC, 0, stream>>>(a_src, a_dst, m, denom, h, bias, out);
}

// Round 2
// 606.940 us; speedup vs baseline: 2.4336x; 2.4336x over previous
//
#include <hip/hip_runtime.h>

#define IN_CH 64
#define HC 128          // HEADS * OUT_CH
#define NHEAD 4
#define NEG 0.2f
#define SCAN_CHUNK 1024

__device__ __forceinline__ float leaky(float v) { return v >= 0.f ? v : NEG * v; }

// One block (128 threads) per node: h[n] = x[n] @ W ; a_src/a_dst reductions.
__global__ void k_transform(const float* __restrict__ x, const float* __restrict__ W,
                            const float* __restrict__ att_src, const float* __restrict__ att_dst,
                            float* __restrict__ h, float* __restrict__ a_src,
                            float* __restrict__ a_dst) {
    const int n = blockIdx.x;
    const int t = threadIdx.x;           // 0..127
    __shared__ float xs[IN_CH];
    if (t < IN_CH) xs[t] = x[(size_t)n * IN_CH + t];
    __syncthreads();
    float acc = 0.f;
#pragma unroll
    for (int k = 0; k < IN_CH; ++k)
        acc = fmaf(xs[k], W[k * HC + t], acc);
    h[(size_t)n * HC + t] = acc;

    float ps = acc * att_src[t];
    float pd = acc * att_dst[t];
#pragma unroll
    for (int off = 16; off > 0; off >>= 1) {
        ps += __shfl_down(ps, off, 32);
        pd += __shfl_down(pd, off, 32);
    }
    if ((t & 31) == 0) {
        a_src[n * NHEAD + (t >> 5)] = ps;
        a_dst[n * NHEAD + (t >> 5)] = pd;
    }
}

// ---------------- CSR build ----------------
__global__ void k_count(const int* __restrict__ dst, int* __restrict__ deg, int E) {
    int e = blockIdx.x * blockDim.x + threadIdx.x;
    if (e < E) atomicAdd(&deg[dst[e]], 1);
}

// per-chunk sums (chunk = 1024 elems, 256 threads x 4)
__global__ void k_chunk_sum(const int* __restrict__ deg, int* __restrict__ bsum, int N) {
    const int t = threadIdx.x;
    int base = blockIdx.x * SCAN_CHUNK + t * 4;
    int s = 0;
#pragma unroll
    for (int k = 0; k < 4; ++k) s += (base + k < N) ? deg[base + k] : 0;
    __shared__ int sh[256];
    sh[t] = s; __syncthreads();
    for (int off = 128; off > 0; off >>= 1) {
        if (t < off) sh[t] += sh[t + off];
        __syncthreads();
    }
    if (t == 0) bsum[blockIdx.x] = sh[0];
}

// serial exclusive scan of the (small) chunk sums; also writes rowptr[N] = E
__global__ void k_scan_bsums(const int* __restrict__ bsum, int* __restrict__ bscan,
                             int* __restrict__ rowptr, int NB, int N) {
    if (threadIdx.x == 0 && blockIdx.x == 0) {
        int run = 0;
        for (int i = 0; i < NB; ++i) { bscan[i] = run; run += bsum[i]; }
        rowptr[N] = run;
    }
}

// local exclusive scan per chunk + chunk offset -> rowptr & cursor
__global__ void k_scan_final(const int* __restrict__ deg, const int* __restrict__ bscan,
                             int* __restrict__ rowptr, int* __restrict__ cursor, int N) {
    const int t = threadIdx.x;
    int base = blockIdx.x * SCAN_CHUNK + t * 4;
    int v[4]; int tsum = 0;
#pragma unroll
    for (int k = 0; k < 4; ++k) { v[k] = (base + k < N) ? deg[base + k] : 0; tsum += v[k]; }
    __shared__ int sh[256];
    sh[t] = tsum; __syncthreads();
    // Hillis-Steele inclusive scan
    for (int off = 1; off < 256; off <<= 1) {
        int add = (t >= off) ? sh[t - off] : 0;
        __syncthreads();
        sh[t] += add;
        __syncthreads();
    }
    int run = sh[t] - tsum + bscan[blockIdx.x];
#pragma unroll
    for (int k = 0; k < 4; ++k) {
        if (base + k < N) { rowptr[base + k] = run; cursor[base + k] = run; run += v[k]; }
    }
}

__global__ void k_fill(const int* __restrict__ src, const int* __restrict__ dst,
                       int* __restrict__ cursor, int* __restrict__ srcbuf, int E) {
    int e = blockIdx.x * blockDim.x + threadIdx.x;
    if (e < E) {
        int p = atomicAdd(&cursor[dst[e]], 1);
        srcbuf[p] = src[e];
    }
}

// ---------------- fused per-node kernel: one wave per node ----------------
// softmax over in-edges (+ self loop) per head, aggregate h[src], bias, log_softmax.
__global__ void __launch_bounds__(256) k_node(
        const int* __restrict__ rowptr, const int* __restrict__ srcbuf,
        const float* __restrict__ a_src, const float* __restrict__ a_dst,
        const float* __restrict__ h, const float* __restrict__ bias,
        float* __restrict__ out, int N) {
    const int lane = threadIdx.x & 63;
    const int n = blockIdx.x * (blockDim.x >> 6) + (threadIdx.x >> 6);
    if (n >= N) return;
    const int start = rowptr[n], end = rowptr[n + 1];
    const int deg = end - start;
    const int myh = lane & 3;            // head for passes A/B

    const float ad  = a_dst[n * NHEAD + myh];
    const float asf = a_src[n * NHEAD + myh];
    const float eself = leaky(asf + ad);

    // pass A: per-head max (init with self-loop score)
    float mx = eself;
    for (int j = lane >> 2; j < deg; j += 16) {
        int s = srcbuf[start + j];
        mx = fmaxf(mx, leaky(a_src[s * NHEAD + myh] + ad));
    }
#pragma unroll
    for (int off = 4; off < 64; off <<= 1) mx = fmaxf(mx, __shfl_xor(mx, off, 64));

    // pass B: per-head sum of exp(e - m)
    float sm = (lane < 4) ? __expf(eself - mx) : 0.f;
    for (int j = lane >> 2; j < deg; j += 16) {
        int s = srcbuf[start + j];
        sm += __expf(leaky(a_src[s * NHEAD + myh] + ad) - mx);
    }
#pragma unroll
    for (int off = 4; off < 64; off <<= 1) sm += __shfl_xor(sm, off, 64);
    const float rden = 1.f / (sm + 1e-16f);

    // broadcast per-channel head params. channel c0 = lane (heads 0/1), c1 = lane+64 (heads 2/3)
    const int h0 = lane >> 5, h1 = 2 + (lane >> 5);
    const float m0 = __shfl(mx, h0, 64),   m1 = __shfl(mx, h1, 64);
    const float r0 = __shfl(rden, h0, 64), r1 = __shfl(rden, h1, 64);
    const float ad0 = __shfl(ad, h0, 64),  ad1 = __shfl(ad, h1, 64);

    // pass C: gather-aggregate
    float acc0 = 0.f, acc1 = 0.f;
    for (int j = 0; j < deg; ++j) {
        const int s = srcbuf[start + j];
        const size_t sb = (size_t)s * HC;
        float as0 = a_src[s * NHEAD + h0];
        float as1 = a_src[s * NHEAD + h1];
        float al0 = __expf(leaky(as0 + ad0) - m0) * r0;
        float al1 = __expf(leaky(as1 + ad1) - m1) * r1;
        acc0 = fmaf(al0, h[sb + lane], acc0);
        acc1 = fmaf(al1, h[sb + 64 + lane], acc1);
    }
    // self loop
    {
        const size_t nb = (size_t)n * HC;
        float e0 = __shfl(eself, h0, 64), e1 = __shfl(eself, h1, 64);
        acc0 = fmaf(__expf(e0 - m0) * r0, h[nb + lane], acc0);
        acc1 = fmaf(__expf(e1 - m1) * r1, h[nb + 64 + lane], acc1);
    }

    // bias + log_softmax over 128 channels
    float v0 = acc0 + bias[lane];
    float v1 = acc1 + bias[64 + lane];
    float mxv = fmaxf(v0, v1);
#pragma unroll
    for (int off = 1; off < 64; off <<= 1) mxv = fmaxf(mxv, __shfl_xor(mxv, off, 64));
    float se = __expf(v0 - mxv) + __expf(v1 - mxv);
#pragma unroll
    for (int off = 1; off < 64; off <<= 1) se += __shfl_xor(se, off, 64);
    const float lse = mxv + __logf(se);
    const size_t ob = (size_t)n * HC;
    out[ob + lane]      = v0 - lse;
    out[ob + 64 + lane] = v1 - lse;
}

extern "C" void kernel_launch(void* const* d_in, const int* in_sizes, int n_in,
                              void* d_out, int out_size, void* d_ws, size_t ws_size,
                              hipStream_t stream) {
    const float* x       = (const float*)d_in[0];
    const int*   ei      = (const int*)d_in[1];
    const float* W       = (const float*)d_in[2];
    const float* att_src = (const float*)d_in[3];
    const float* att_dst = (const float*)d_in[4];
    const float* bias    = (const float*)d_in[5];
    float* out = (float*)d_out;

    const int N = in_sizes[0] / IN_CH;     // 100000
    const int E = in_sizes[1] / 2;         // 1600000
    const int* src = ei;
    const int* dst = ei + E;
    const int NB = (N + SCAN_CHUNK - 1) / SCAN_CHUNK;

    char* wsb = (char*)d_ws;
    float* h      = (float*)wsb;                    wsb += (size_t)N * HC * 4;
    float* a_src  = (float*)wsb;                    wsb += (size_t)N * NHEAD * 4;
    float* a_dst  = (float*)wsb;                    wsb += (size_t)N * NHEAD * 4;
    int*   rowptr = (int*)wsb;                      wsb += (size_t)(N + 1) * 4;
    int*   cursor = (int*)wsb;                      wsb += (size_t)N * 4;
    int*   deg    = (int*)wsb;                      wsb += (size_t)N * 4;
    int*   srcbuf = (int*)wsb;                      wsb += (size_t)E * 4;
    int*   bsum   = (int*)wsb;                      wsb += (size_t)NB * 4;
    int*   bscan  = (int*)wsb;                      wsb += (size_t)NB * 4;

    hipMemsetAsync(deg, 0, (size_t)N * 4, stream);

    k_transform<<<N, HC, 0, stream>>>(x, W, att_src, att_dst, h, a_src, a_dst);

    k_count<<<(E + 255) / 256, 256, 0, stream>>>(dst, deg, E);
    k_chunk_sum<<<NB, 256, 0, stream>>>(deg, bsum, N);
    k_scan_bsums<<<1, 64, 0, stream>>>(bsum, bscan, rowptr, NB, N);
    k_scan_final<<<NB, 256, 0, stream>>>(deg, bscan, rowptr, cursor, N);
    k_fill<<<(E + 255) / 256, 256, 0, stream>>>(src, dst, cursor, srcbuf, E);

    k_node<<<(N + 3) / 4, 256, 0, stream>>>(rowptr, srcbuf, a_src, a_dst, h, bias, out, N);
}